// Round 4
// baseline (23771.762 us; speedup 1.0000x reference)
//
#include <hip/hip_runtime.h>
#include <hip/hip_bf16.h>
#include <math.h>

#define B_   32
#define N_   256
#define S_   257
#define D_   768
#define FF_  3072
#define H_   12
#define HD_  64
#define L_   6
#define NA_  512
#define ND_  512
#define NE_  512
#define NS_  512
#define SCALE_ 0.125f
#define EPS_ 1e-5f
#define NEG_BIG_ (-1e30f)

typedef __hip_bfloat16 bf16;

static __device__ __forceinline__ int iclamp(int v, int lo, int hi) {
    return v < lo ? lo : (v > hi ? hi : v);
}
static __device__ __forceinline__ float b2f(bf16 v) { return (float)v; }
static __device__ __forceinline__ float ldA(const float* p, size_t i) { return p[i]; }
static __device__ __forceinline__ float ldA(const bf16* p, size_t i) { return b2f(p[i]); }

// ---------------------------------------------------------------- embedding
__global__ __launch_bounds__(256) void embed_kernel(
    const int* __restrict__ x, const int* __restrict__ indeg,
    const int* __restrict__ outdeg, const float* __restrict__ atom_emb,
    const float* __restrict__ ine, const float* __restrict__ oute,
    const float* __restrict__ gtok, float* __restrict__ h)
{
    int row = blockIdx.x;           // b*S + s
    int b = row / S_, s = row % S_;
    int t = threadIdx.x;
    float* hr = h + (size_t)row * D_;
    if (s == 0) {
        for (int d = t; d < D_; d += 256) hr[d] = gtok[d];
        return;
    }
    int n = s - 1;
    size_t xb = ((size_t)b * N_ + n) * 3;
    int i0 = iclamp(x[xb + 0], 0, NA_);
    int i1 = iclamp(x[xb + 1], 0, NA_);
    int i2 = iclamp(x[xb + 2], 0, NA_);
    int id = iclamp(indeg[(size_t)b * N_ + n], 0, ND_ - 1);
    int od = iclamp(outdeg[(size_t)b * N_ + n], 0, ND_ - 1);
    const float* a0 = atom_emb + (size_t)i0 * D_;
    const float* a1 = atom_emb + (size_t)i1 * D_;
    const float* a2 = atom_emb + (size_t)i2 * D_;
    const float* pi = ine + (size_t)id * D_;
    const float* po = oute + (size_t)od * D_;
    for (int d = t; d < D_; d += 256)
        hr[d] = a0[d] + a1[d] + a2[d] + pi[d] + po[d];
}

// ---------------------------------------------------------------- attn bias
// bias(b,h,q,k) stored bf16; masked keys -1e30 (exp underflows to exactly 0)
__global__ __launch_bounds__(256) void bias_kernel(
    const int* __restrict__ x, const float* __restrict__ ab,
    const int* __restrict__ sp, const int* __restrict__ et,
    const float* __restrict__ spemb, const float* __restrict__ eemb,
    const float* __restrict__ virt, bf16* __restrict__ bias)
{
    int row = blockIdx.x;           // b*S + q
    int b = row / S_, q = row % S_;
    for (int k = threadIdx.x; k < S_; k += 256) {
        float abv = ab[((size_t)b * S_ + q) * S_ + k];
        bool masked = (k >= 1) && (x[((size_t)b * N_ + (k - 1)) * 3] == 0);
        size_t out_base = (size_t)b * H_ * S_ * S_ + (size_t)q * S_ + k;
        if (masked) {
            #pragma unroll
            for (int hh = 0; hh < H_; hh++)
                bias[out_base + (size_t)hh * S_ * S_] = __float2bfloat16(NEG_BIG_);
        } else if (q == 0 || k == 0) {
            #pragma unroll
            for (int hh = 0; hh < H_; hh++)
                bias[out_base + (size_t)hh * S_ * S_] = __float2bfloat16(abv + virt[hh]);
        } else {
            int spv = iclamp(sp[((size_t)b * N_ + (q - 1)) * N_ + (k - 1)], 0, NS_ - 1);
            size_t eb = (((size_t)b * N_ + (q - 1)) * N_ + (k - 1)) * 3;
            int e0 = iclamp(et[eb + 0], 0, NE_);
            int e1 = iclamp(et[eb + 1], 0, NE_);
            int e2 = iclamp(et[eb + 2], 0, NE_);
            #pragma unroll
            for (int hh = 0; hh < H_; hh++) {
                float inner = spemb[spv * H_ + hh]
                    + (eemb[e0 * H_ + hh] + eemb[e1 * H_ + hh] + eemb[e2 * H_ + hh]) * (1.0f / 3.0f);
                bias[out_base + (size_t)hh * S_ * S_] = __float2bfloat16(abv + inner);
            }
        }
    }
}

// ---------------------------------------------------------------- layernorm
__global__ __launch_bounds__(256) void ln_kernel(
    const float* __restrict__ x, float* __restrict__ y,
    const float* __restrict__ g, const float* __restrict__ b)
{
    int row = blockIdx.x;
    int t = threadIdx.x;
    const float* xr = x + (size_t)row * D_;
    float* yr = y + (size_t)row * D_;
    float v0 = xr[t], v1 = xr[t + 256], v2 = xr[t + 512];
    __shared__ float rs[256], rq[256];
    rs[t] = v0 + v1 + v2;
    rq[t] = v0 * v0 + v1 * v1 + v2 * v2;
    __syncthreads();
    for (int o = 128; o > 0; o >>= 1) {
        if (t < o) { rs[t] += rs[t + o]; rq[t] += rq[t + o]; }
        __syncthreads();
    }
    float mean = rs[0] * (1.0f / D_);
    float var = fmaxf(rq[0] * (1.0f / D_) - mean * mean, 0.f);
    float inv = rsqrtf(var + EPS_);
    yr[t]       = (v0 - mean) * inv * g[t]       + b[t];
    yr[t + 256] = (v1 - mean) * inv * g[t + 256] + b[t + 256];
    yr[t + 512] = (v2 - mean) * inv * g[t + 512] + b[t + 512];
}

// ---------------------------------------------------------------- final LN + split
__global__ __launch_bounds__(256) void final_ln_kernel(
    const float* __restrict__ x, const float* __restrict__ g,
    const float* __restrict__ b, float* __restrict__ out)
{
    int row = blockIdx.x;
    int bb = row / S_, s = row % S_;
    int t = threadIdx.x;
    const float* xr = x + (size_t)row * D_;
    float v0 = xr[t], v1 = xr[t + 256], v2 = xr[t + 512];
    __shared__ float rs[256], rq[256];
    rs[t] = v0 + v1 + v2;
    rq[t] = v0 * v0 + v1 * v1 + v2 * v2;
    __syncthreads();
    for (int o = 128; o > 0; o >>= 1) {
        if (t < o) { rs[t] += rs[t + o]; rq[t] += rq[t + o]; }
        __syncthreads();
    }
    float mean = rs[0] * (1.0f / D_);
    float var = fmaxf(rq[0] * (1.0f / D_) - mean * mean, 0.f);
    float inv = rsqrtf(var + EPS_);
    float* dst = (s == 0) ? out + (size_t)B_ * N_ * D_ + (size_t)bb * D_
                          : out + ((size_t)bb * N_ + (s - 1)) * D_;
    dst[t]       = (v0 - mean) * inv * g[t]       + b[t];
    dst[t + 256] = (v1 - mean) * inv * g[t + 256] + b[t + 256];
    dst[t + 512] = (v2 - mean) * inv * g[t + 512] + b[t + 512];
}

// ---------------------------------------------------------------- GEMM
// C[m,n] = sum_k A[m,k] * W[n,k] + bias[n]
// MODE 0: plain  1: *scale  2: exact gelu  3: + res[m,n] (f32)
template <typename TA, typename TC, int MODE>
__global__ __launch_bounds__(256) void gemm_kernel(
    const TA* __restrict__ A, const float* __restrict__ W,
    const float* __restrict__ bias, const float* __restrict__ res,
    TC* __restrict__ C, int M, int N, int K, float scale)
{
    __shared__ float As[16][68];
    __shared__ float Ws[16][68];
    int tid = threadIdx.x;
    int tx = tid % 16, ty = tid / 16;
    int block_m = blockIdx.x * 64;
    int block_n = blockIdx.y * 64;

    float acc[4][4] = {{0.f}};

    int lk = tid % 16;
    int lm = tid / 16;
    for (int k0 = 0; k0 < K; k0 += 16) {
        #pragma unroll
        for (int i = 0; i < 4; i++) {
            int m = lm + i * 16;
            int gm = block_m + m;
            As[lk][m] = (gm < M) ? ldA(A, (size_t)gm * K + k0 + lk) : 0.f;
        }
        #pragma unroll
        for (int i = 0; i < 4; i++) {
            int n = lm + i * 16;
            Ws[lk][n] = W[(size_t)(block_n + n) * K + k0 + lk];
        }
        __syncthreads();
        #pragma unroll
        for (int kk = 0; kk < 16; kk++) {
            float4 av = *reinterpret_cast<const float4*>(&As[kk][ty * 4]);
            float4 bv = *reinterpret_cast<const float4*>(&Ws[kk][tx * 4]);
            float a[4] = {av.x, av.y, av.z, av.w};
            float bb[4] = {bv.x, bv.y, bv.z, bv.w};
            #pragma unroll
            for (int i = 0; i < 4; i++)
                #pragma unroll
                for (int j = 0; j < 4; j++)
                    acc[i][j] = fmaf(a[i], bb[j], acc[i][j]);
        }
        __syncthreads();
    }

    #pragma unroll
    for (int i = 0; i < 4; i++) {
        int gm = block_m + ty * 4 + i;
        if (gm >= M) continue;
        #pragma unroll
        for (int j = 0; j < 4; j++) {
            int gn = block_n + tx * 4 + j;
            float val = acc[i][j] + bias[gn];
            if (MODE == 1) val *= scale;
            if (MODE == 2) val = 0.5f * val * (1.0f + erff(val * 0.70710678118654752f));
            if (MODE == 3) val += res[(size_t)gm * N + gn];
            C[(size_t)gm * N + gn] = (TC)val;
        }
    }
}

// ---------------------------------------------------------------- attention
__global__ __launch_bounds__(256) void attn_kernel(
    const float* __restrict__ qb, const float* __restrict__ kb,
    const float* __restrict__ vb, const bf16* __restrict__ bias,
    float* __restrict__ ob)
{
    int idx = blockIdx.x;
    int qrow = idx % S_;
    int bh = idx / S_;             // b*H + h
    int hh = bh % H_;
    int b = bh / H_;
    int t = threadIdx.x;

    __shared__ float qsh[HD_];
    __shared__ float psh[S_];
    __shared__ float red[256];
    __shared__ float oacc[4][HD_];

    const float* qptr = qb + ((size_t)b * S_ + qrow) * D_ + hh * HD_;
    if (t < HD_) qsh[t] = qptr[t];
    __syncthreads();

    float lmax = NEG_BIG_;
    for (int k = t; k < S_; k += 256) {
        const float* kp = kb + ((size_t)b * S_ + k) * D_ + hh * HD_;
        float s = b2f(bias[((size_t)bh * S_ + qrow) * S_ + k]);
        float dot = 0.f;
        #pragma unroll
        for (int d = 0; d < HD_; d += 4) {
            float4 kv = *reinterpret_cast<const float4*>(kp + d);
            dot += qsh[d] * kv.x + qsh[d + 1] * kv.y + qsh[d + 2] * kv.z + qsh[d + 3] * kv.w;
        }
        s += dot;
        psh[k] = s;
        lmax = fmaxf(lmax, s);
    }
    red[t] = lmax;
    __syncthreads();
    for (int o = 128; o > 0; o >>= 1) {
        if (t < o) red[t] = fmaxf(red[t], red[t + o]);
        __syncthreads();
    }
    float gmax = red[0];
    __syncthreads();

    float lsum = 0.f;
    for (int k = t; k < S_; k += 256) {
        float e = __expf(psh[k] - gmax);
        psh[k] = e;
        lsum += e;
    }
    red[t] = lsum;
    __syncthreads();
    for (int o = 128; o > 0; o >>= 1) {
        if (t < o) red[t] += red[t + o];
        __syncthreads();
    }
    float inv = 1.0f / fmaxf(red[0], 1e-30f);
    __syncthreads();

    int d = t % HD_;
    int part = t / HD_;
    float acc = 0.f;
    for (int k = part; k < S_; k += 4)
        acc += psh[k] * vb[((size_t)b * S_ + k) * D_ + hh * HD_ + d];
    oacc[part][d] = acc;
    __syncthreads();
    if (t < HD_) {
        float tot = (oacc[0][t] + oacc[1][t] + oacc[2][t] + oacc[3][t]) * inv;
        ob[((size_t)b * S_ + qrow) * D_ + hh * HD_ + t] = tot;
    }
}

// ---------------------------------------------------------------- launch
extern "C" void kernel_launch(void* const* d_in, const int* in_sizes, int n_in,
                              void* d_out, int out_size, void* d_ws, size_t ws_size,
                              hipStream_t stream)
{
    const int*   x         = (const int*)d_in[0];
    const float* attn_bias = (const float*)d_in[1];
    const int*   spatial   = (const int*)d_in[2];
    const int*   edget     = (const int*)d_in[3];
    const int*   indeg     = (const int*)d_in[4];
    const int*   outdeg    = (const int*)d_in[5];
    const float* atom_emb  = (const float*)d_in[6];
    const float* ine       = (const float*)d_in[7];
    const float* oute      = (const float*)d_in[8];
    const float* gtok      = (const float*)d_in[9];
    const float* spemb     = (const float*)d_in[10];
    const float* eemb      = (const float*)d_in[11];
    const float* virt      = (const float*)d_in[12];
    const float* Wq        = (const float*)d_in[13];
    const float* Wk        = (const float*)d_in[14];
    const float* Wv        = (const float*)d_in[15];
    const float* Wo        = (const float*)d_in[16];
    const float* bq        = (const float*)d_in[17];
    const float* bk        = (const float*)d_in[18];
    const float* bvv       = (const float*)d_in[19];
    const float* bo        = (const float*)d_in[20];
    const float* ln1g      = (const float*)d_in[21];
    const float* ln1b      = (const float*)d_in[22];
    const float* ln2g      = (const float*)d_in[23];
    const float* ln2b      = (const float*)d_in[24];
    const float* W1        = (const float*)d_in[25];
    const float* b1        = (const float*)d_in[26];
    const float* W2        = (const float*)d_in[27];
    const float* b2        = (const float*)d_in[28];
    const float* fing      = (const float*)d_in[29];
    const float* finb      = (const float*)d_in[30];

    const int M = B_ * S_;          // 8224
    char* wsp = (char*)d_ws;
    size_t off = 0;
    auto alloc = [&](size_t bytes) -> void* {
        void* p = (void*)(wsp + off);
        off += (bytes + 255) & ~(size_t)255;
        return p;
    };
    // ws budget (proven safe <= 190 MB):
    // h 25.3 + z 25.3 + q/k/v 75.8 (fbuf bf16 50.5 aliases this) + bias bf16 50.7 = ~177 MB
    float* h    = (float*)alloc((size_t)M * D_ * 4);
    float* z    = (float*)alloc((size_t)M * D_ * 4);   // also obuf
    float* qbuf = (float*)alloc((size_t)M * D_ * 4);
    float* kbuf = (float*)alloc((size_t)M * D_ * 4);
    float* vbuf = (float*)alloc((size_t)M * D_ * 4);
    bf16*  bias = (bf16*)alloc((size_t)B_ * H_ * S_ * S_ * 2);
    float* obuf = z;                                   // z dead after V-GEMM
    bf16*  fbuf = (bf16*)qbuf;                         // qkv dead after attn; 50.5 MB fits in 75.8 MB

    embed_kernel<<<M, 256, 0, stream>>>(x, indeg, outdeg, atom_emb, ine, oute, gtok, h);
    bias_kernel<<<M, 256, 0, stream>>>(x, attn_bias, spatial, edget, spemb, eemb, virt, bias);

    dim3 gD((M + 63) / 64, D_ / 64);
    dim3 gF((M + 63) / 64, FF_ / 64);

    for (int l = 0; l < L_; l++) {
        ln_kernel<<<M, 256, 0, stream>>>(h, z, ln1g + l * D_, ln1b + l * D_);
        gemm_kernel<float, float, 1><<<gD, 256, 0, stream>>>(z, Wq + (size_t)l * D_ * D_, bq + l * D_, nullptr, qbuf, M, D_, D_, SCALE_);
        gemm_kernel<float, float, 0><<<gD, 256, 0, stream>>>(z, Wk + (size_t)l * D_ * D_, bk + l * D_, nullptr, kbuf, M, D_, D_, 1.f);
        gemm_kernel<float, float, 0><<<gD, 256, 0, stream>>>(z, Wv + (size_t)l * D_ * D_, bvv + l * D_, nullptr, vbuf, M, D_, D_, 1.f);
        attn_kernel<<<B_ * H_ * S_, 256, 0, stream>>>(qbuf, kbuf, vbuf, bias, obuf);
        gemm_kernel<float, float, 3><<<gD, 256, 0, stream>>>(obuf, Wo + (size_t)l * D_ * D_, bo + l * D_, h, h, M, D_, D_, 1.f);
        ln_kernel<<<M, 256, 0, stream>>>(h, z, ln2g + l * D_, ln2b + l * D_);
        gemm_kernel<float, bf16, 2><<<gF, 256, 0, stream>>>(z, W1 + (size_t)l * FF_ * D_, b1 + l * FF_, nullptr, fbuf, M, FF_, D_, 1.f);
        gemm_kernel<bf16, float, 3><<<gD, 256, 0, stream>>>(fbuf, W2 + (size_t)l * D_ * FF_, b2 + l * D_, h, h, M, D_, FF_, 1.f);
    }
    final_ln_kernel<<<M, 256, 0, stream>>>(h, fing, finb, (float*)d_out);
}

// Round 5
// 6374.416 us; speedup vs baseline: 3.7292x; 3.7292x over previous
//
#include <hip/hip_runtime.h>
#include <hip/hip_bf16.h>
#include <math.h>

#define B_   32
#define N_   256
#define S_   257
#define D_   768
#define FF_  3072
#define H_   12
#define HD_  64
#define L_   6
#define NA_  512
#define ND_  512
#define NE_  512
#define NS_  512
#define SCALE_ 0.125f
#define EPS_ 1e-5f
#define NEG_BIG_ (-1e30f)

typedef __hip_bfloat16 bf16;
typedef __attribute__((ext_vector_type(8))) short bf16x8;
typedef __attribute__((ext_vector_type(4))) float f32x4;

static __device__ __forceinline__ int iclamp(int v, int lo, int hi) {
    return v < lo ? lo : (v > hi ? hi : v);
}
static __device__ __forceinline__ float b2f(bf16 v) { return (float)v; }
static __device__ __forceinline__ short f2b(float f) {
    union { bf16 b; short s; } u; u.b = __float2bfloat16(f); return u.s;
}
static __device__ __forceinline__ float blo(unsigned u) { return __uint_as_float(u << 16); }
static __device__ __forceinline__ float bhi(unsigned u) { return __uint_as_float(u & 0xFFFF0000u); }
static __device__ __forceinline__ float s2f(short s) {
    return __uint_as_float(((unsigned)(unsigned short)s) << 16);
}

// ---------------------------------------------------------------- embedding
__global__ __launch_bounds__(256) void embed_kernel(
    const int* __restrict__ x, const int* __restrict__ indeg,
    const int* __restrict__ outdeg, const float* __restrict__ atom_emb,
    const float* __restrict__ ine, const float* __restrict__ oute,
    const float* __restrict__ gtok, float* __restrict__ h)
{
    int row = blockIdx.x;           // b*S + s
    int b = row / S_, s = row % S_;
    int t = threadIdx.x;
    float* hr = h + (size_t)row * D_;
    if (s == 0) {
        for (int d = t; d < D_; d += 256) hr[d] = gtok[d];
        return;
    }
    int n = s - 1;
    size_t xb = ((size_t)b * N_ + n) * 3;
    int i0 = iclamp(x[xb + 0], 0, NA_);
    int i1 = iclamp(x[xb + 1], 0, NA_);
    int i2 = iclamp(x[xb + 2], 0, NA_);
    int id = iclamp(indeg[(size_t)b * N_ + n], 0, ND_ - 1);
    int od = iclamp(outdeg[(size_t)b * N_ + n], 0, ND_ - 1);
    const float* a0 = atom_emb + (size_t)i0 * D_;
    const float* a1 = atom_emb + (size_t)i1 * D_;
    const float* a2 = atom_emb + (size_t)i2 * D_;
    const float* pi = ine + (size_t)id * D_;
    const float* po = oute + (size_t)od * D_;
    for (int d = t; d < D_; d += 256)
        hr[d] = a0[d] + a1[d] + a2[d] + pi[d] + po[d];
}

// ---------------------------------------------------------------- attn bias
__global__ __launch_bounds__(256) void bias_kernel(
    const int* __restrict__ x, const float* __restrict__ ab,
    const int* __restrict__ sp, const int* __restrict__ et,
    const float* __restrict__ spemb, const float* __restrict__ eemb,
    const float* __restrict__ virt, bf16* __restrict__ bias)
{
    int row = blockIdx.x;           // b*S + q
    int b = row / S_, q = row % S_;
    for (int k = threadIdx.x; k < S_; k += 256) {
        float abv = ab[((size_t)b * S_ + q) * S_ + k];
        bool masked = (k >= 1) && (x[((size_t)b * N_ + (k - 1)) * 3] == 0);
        size_t out_base = (size_t)b * H_ * S_ * S_ + (size_t)q * S_ + k;
        if (masked) {
            #pragma unroll
            for (int hh = 0; hh < H_; hh++)
                bias[out_base + (size_t)hh * S_ * S_] = __float2bfloat16(NEG_BIG_);
        } else if (q == 0 || k == 0) {
            #pragma unroll
            for (int hh = 0; hh < H_; hh++)
                bias[out_base + (size_t)hh * S_ * S_] = __float2bfloat16(abv + virt[hh]);
        } else {
            int spv = iclamp(sp[((size_t)b * N_ + (q - 1)) * N_ + (k - 1)], 0, NS_ - 1);
            size_t eb = (((size_t)b * N_ + (q - 1)) * N_ + (k - 1)) * 3;
            int e0 = iclamp(et[eb + 0], 0, NE_);
            int e1 = iclamp(et[eb + 1], 0, NE_);
            int e2 = iclamp(et[eb + 2], 0, NE_);
            #pragma unroll
            for (int hh = 0; hh < H_; hh++) {
                float inner = spemb[spv * H_ + hh]
                    + (eemb[e0 * H_ + hh] + eemb[e1 * H_ + hh] + eemb[e2 * H_ + hh]) * (1.0f / 3.0f);
                bias[out_base + (size_t)hh * S_ * S_] = __float2bfloat16(abv + inner);
            }
        }
    }
}

// ---------------------------------------------------------------- layernorm
__global__ __launch_bounds__(256) void ln_kernel(
    const float* __restrict__ x, float* __restrict__ y,
    const float* __restrict__ g, const float* __restrict__ b)
{
    int row = blockIdx.x;
    int t = threadIdx.x;
    const float* xr = x + (size_t)row * D_;
    float* yr = y + (size_t)row * D_;
    float v0 = xr[t], v1 = xr[t + 256], v2 = xr[t + 512];
    __shared__ float rs[256], rq[256];
    rs[t] = v0 + v1 + v2;
    rq[t] = v0 * v0 + v1 * v1 + v2 * v2;
    __syncthreads();
    for (int o = 128; o > 0; o >>= 1) {
        if (t < o) { rs[t] += rs[t + o]; rq[t] += rq[t + o]; }
        __syncthreads();
    }
    float mean = rs[0] * (1.0f / D_);
    float var = fmaxf(rq[0] * (1.0f / D_) - mean * mean, 0.f);
    float inv = rsqrtf(var + EPS_);
    yr[t]       = (v0 - mean) * inv * g[t]       + b[t];
    yr[t + 256] = (v1 - mean) * inv * g[t + 256] + b[t + 256];
    yr[t + 512] = (v2 - mean) * inv * g[t + 512] + b[t + 512];
}

// ---------------------------------------------------------------- final LN + split
__global__ __launch_bounds__(256) void final_ln_kernel(
    const float* __restrict__ x, const float* __restrict__ g,
    const float* __restrict__ b, float* __restrict__ out)
{
    int row = blockIdx.x;
    int bb = row / S_, s = row % S_;
    int t = threadIdx.x;
    const float* xr = x + (size_t)row * D_;
    float v0 = xr[t], v1 = xr[t + 256], v2 = xr[t + 512];
    __shared__ float rs[256], rq[256];
    rs[t] = v0 + v1 + v2;
    rq[t] = v0 * v0 + v1 * v1 + v2 * v2;
    __syncthreads();
    for (int o = 128; o > 0; o >>= 1) {
        if (t < o) { rs[t] += rs[t + o]; rq[t] += rq[t + o]; }
        __syncthreads();
    }
    float mean = rs[0] * (1.0f / D_);
    float var = fmaxf(rq[0] * (1.0f / D_) - mean * mean, 0.f);
    float inv = rsqrtf(var + EPS_);
    float* dst = (s == 0) ? out + (size_t)B_ * N_ * D_ + (size_t)bb * D_
                          : out + ((size_t)bb * N_ + (s - 1)) * D_;
    dst[t]       = (v0 - mean) * inv * g[t]       + b[t];
    dst[t + 256] = (v1 - mean) * inv * g[t + 256] + b[t + 256];
    dst[t + 512] = (v2 - mean) * inv * g[t + 512] + b[t + 512];
}

// ---------------------------------------------------------------- MFMA GEMM
// C[m,n] = sum_k A[m,k] * W[n,k] + bias[n]
// 128x128 block tile, 4 waves, each wave 64x64 (4x4 of 16x16x32 MFMA).
// LDS row stride 40 bf16 (=20 dwords): 8-lane subgroups hit all 32 banks.
// MODE 0: plain  1: *scale  2: exact gelu  3: + res[m,n] (f32)
template <typename TA, typename TC, int MODE>
__global__ __launch_bounds__(256) void mgemm(
    const TA* __restrict__ A, const float* __restrict__ W,
    const float* __restrict__ bias, const float* __restrict__ res,
    TC* __restrict__ C, int M, int N, int K, float scale)
{
    __shared__ short As[128 * 40];
    __shared__ short Ws[128 * 40];
    const int t = threadIdx.x;
    const int lane = t & 63;
    const int w = t >> 6;
    const int wm = w & 1, wn = w >> 1;
    const int quad = lane >> 4;
    const int col = lane & 15;
    const int block_m = blockIdx.x * 128;
    const int block_n = blockIdx.y * 128;

    f32x4 acc[4][4];
    #pragma unroll
    for (int i = 0; i < 4; i++)
        #pragma unroll
        for (int j = 0; j < 4; j++)
            acc[i][j] = (f32x4){0.f, 0.f, 0.f, 0.f};

    for (int k0 = 0; k0 < K; k0 += 32) {
        // stage A tile (128 x 32) -> bf16 LDS
        #pragma unroll
        for (int ss = 0; ss < 2; ss++) {
            int s = t + ss * 256;
            int row = s >> 2, cg = s & 3;
            int gm = block_m + row;
            bf16x8 v = {0, 0, 0, 0, 0, 0, 0, 0};
            if (gm < M) {
                if constexpr (sizeof(TA) == 4) {
                    const float* ap = (const float*)A + (size_t)gm * K + k0 + cg * 8;
                    float4 x0 = *(const float4*)ap;
                    float4 x1 = *(const float4*)(ap + 4);
                    v = (bf16x8){f2b(x0.x), f2b(x0.y), f2b(x0.z), f2b(x0.w),
                                 f2b(x1.x), f2b(x1.y), f2b(x1.z), f2b(x1.w)};
                } else {
                    v = *(const bf16x8*)((const short*)A + (size_t)gm * K + k0 + cg * 8);
                }
            }
            *(bf16x8*)&As[row * 40 + cg * 8] = v;
        }
        // stage W tile (128 x 32) -> bf16 LDS (N multiple of 128, no guard)
        #pragma unroll
        for (int ss = 0; ss < 2; ss++) {
            int s = t + ss * 256;
            int row = s >> 2, cg = s & 3;
            const float* wp = W + (size_t)(block_n + row) * K + k0 + cg * 8;
            float4 x0 = *(const float4*)wp;
            float4 x1 = *(const float4*)(wp + 4);
            bf16x8 v = (bf16x8){f2b(x0.x), f2b(x0.y), f2b(x0.z), f2b(x0.w),
                                f2b(x1.x), f2b(x1.y), f2b(x1.z), f2b(x1.w)};
            *(bf16x8*)&Ws[row * 40 + cg * 8] = v;
        }
        __syncthreads();
        bf16x8 af[4], bfr[4];
        #pragma unroll
        for (int mt = 0; mt < 4; mt++)
            af[mt] = *(const bf16x8*)&As[(wm * 64 + mt * 16 + col) * 40 + quad * 8];
        #pragma unroll
        for (int nt = 0; nt < 4; nt++)
            bfr[nt] = *(const bf16x8*)&Ws[(wn * 64 + nt * 16 + col) * 40 + quad * 8];
        #pragma unroll
        for (int mt = 0; mt < 4; mt++)
            #pragma unroll
            for (int nt = 0; nt < 4; nt++)
                acc[mt][nt] = __builtin_amdgcn_mfma_f32_16x16x32_bf16(
                    af[mt], bfr[nt], acc[mt][nt], 0, 0, 0);
        __syncthreads();
    }

    // epilogue: D row = quad*4 + r, col = lane&15
    #pragma unroll
    for (int mt = 0; mt < 4; mt++) {
        #pragma unroll
        for (int nt = 0; nt < 4; nt++) {
            int gn = block_n + wn * 64 + nt * 16 + col;
            float bn = bias[gn];
            #pragma unroll
            for (int r = 0; r < 4; r++) {
                int gm = block_m + wm * 64 + mt * 16 + quad * 4 + r;
                if (gm < M) {
                    float val = acc[mt][nt][r] + bn;
                    if (MODE == 1) val *= scale;
                    if (MODE == 2) val = 0.5f * val * (1.0f + erff(val * 0.70710678118654752f));
                    if (MODE == 3) val += res[(size_t)gm * N + gn];
                    C[(size_t)gm * N + gn] = (TC)val;
                }
            }
        }
    }
}

// ---------------------------------------------------------------- fused attention
// grid (4 q-quarters, B*H). Two K/V chunks (128 / 129 keys) in LDS (bf16),
// online softmax; state (m,l,o) persisted in LDS across chunks.
__global__ __launch_bounds__(256) void attn2(
    const float* __restrict__ qb, const float* __restrict__ kb,
    const float* __restrict__ vb, const bf16* __restrict__ bias,
    float* __restrict__ ob)
{
    __shared__ short Ksh[130 * 72];      // K[k_loc][d], stride 72 (36 dw -> conflict-free)
    __shared__ short Vt[64 * 136];       // V^T[d][k_loc], stride 136 (68 dw)
    __shared__ float psh[4 * 136];       // per-wave probabilities
    __shared__ float st_o[4 * 17 * 64];  // online-softmax o state
    __shared__ float st_ml[4 * 17 * 2];  // m, l state

    const int t = threadIdx.x;
    const int lane = t & 63;
    const int wv = t >> 6;
    const int quarter = blockIdx.x;
    const int bh = blockIdx.y;
    const int hh = bh % H_;
    const int b = bh / H_;
    const int qs = quarter * 65;
    const int qe = (qs + 65 < S_) ? qs + 65 : S_;

    for (int c = 0; c < 2; c++) {
        const int kbase = c * 128;
        const int nk = c ? 129 : 128;
        // stage K chunk
        for (int seg = t; seg < nk * 8; seg += 256) {
            int kl = seg >> 3, dg = (seg & 7) * 8;
            const float* kp = kb + ((size_t)(b * S_ + kbase + kl)) * D_ + hh * HD_ + dg;
            float4 x0 = *(const float4*)kp;
            float4 x1 = *(const float4*)(kp + 4);
            *(bf16x8*)&Ksh[kl * 72 + dg] =
                (bf16x8){f2b(x0.x), f2b(x0.y), f2b(x0.z), f2b(x0.w),
                         f2b(x1.x), f2b(x1.y), f2b(x1.z), f2b(x1.w)};
        }
        // stage V chunk transposed
        for (int idx = t; idx < nk * 64; idx += 256) {
            int kl = idx >> 6, d = idx & 63;
            Vt[d * 136 + kl] = f2b(vb[((size_t)(b * S_ + kbase + kl)) * D_ + hh * HD_ + d]);
        }
        __syncthreads();

        for (int qi = 0;; qi++) {
            int q = qs + wv + qi * 4;
            if (q >= qe) break;
            // q row (wave-uniform broadcast loads)
            float qv[64];
            const float* qp = qb + ((size_t)(b * S_ + q)) * D_ + hh * HD_;
            #pragma unroll
            for (int i = 0; i < 16; i++) {
                float4 xq = *(const float4*)(qp + i * 4);
                qv[i * 4 + 0] = xq.x; qv[i * 4 + 1] = xq.y;
                qv[i * 4 + 2] = xq.z; qv[i * 4 + 3] = xq.w;
            }
            auto dotk = [&](int kl) -> float {
                float acc = 0.f;
                #pragma unroll
                for (int dg = 0; dg < 8; dg++) {
                    uint4 kr = *(const uint4*)&Ksh[kl * 72 + dg * 8];
                    acc += qv[dg * 8 + 0] * blo(kr.x) + qv[dg * 8 + 1] * bhi(kr.x)
                         + qv[dg * 8 + 2] * blo(kr.y) + qv[dg * 8 + 3] * bhi(kr.y)
                         + qv[dg * 8 + 4] * blo(kr.z) + qv[dg * 8 + 5] * bhi(kr.z)
                         + qv[dg * 8 + 6] * blo(kr.w) + qv[dg * 8 + 7] * bhi(kr.w);
                }
                return acc;
            };
            const bf16* brow = bias + ((size_t)bh * S_ + q) * S_ + kbase;
            float sc0 = dotk(lane)      + b2f(brow[lane]);
            float sc1 = dotk(lane + 64) + b2f(brow[lane + 64]);
            float sc2 = NEG_BIG_;
            if (c == 1 && lane == 0) sc2 = dotk(128) + b2f(brow[128]);

            float m_old = c ? st_ml[(wv * 17 + qi) * 2 + 0] : NEG_BIG_;
            float l_old = c ? st_ml[(wv * 17 + qi) * 2 + 1] : 0.f;
            float o_old = c ? st_o[(wv * 17 + qi) * 64 + lane] : 0.f;

            float mx = fmaxf(fmaxf(sc0, sc1), sc2);
            #pragma unroll
            for (int off = 32; off; off >>= 1) mx = fmaxf(mx, __shfl_xor(mx, off));
            float m_new = fmaxf(m_old, mx);
            float p0 = __expf(sc0 - m_new);
            float p1 = __expf(sc1 - m_new);
            float p2 = (c == 1 && lane == 0) ? __expf(sc2 - m_new) : 0.f;
            float ps = p0 + p1 + p2;
            #pragma unroll
            for (int off = 32; off; off >>= 1) ps += __shfl_xor(ps, off);
            float alpha = __expf(m_old - m_new);
            float l_new = l_old * alpha + ps;

            psh[wv * 136 + lane] = p0;
            psh[wv * 136 + 64 + lane] = p1;
            if (c == 1 && lane == 0) psh[wv * 136 + 128] = p2;
            // wave-synchronous: LDS write->read ordered within wave

            float pv = 0.f;
            #pragma unroll
            for (int kg = 0; kg < 16; kg++) {
                uint4 vr = *(const uint4*)&Vt[lane * 136 + kg * 8];
                float4 pa = *(const float4*)&psh[wv * 136 + kg * 8];
                float4 pb = *(const float4*)&psh[wv * 136 + kg * 8 + 4];
                pv += pa.x * blo(vr.x) + pa.y * bhi(vr.x)
                    + pa.z * blo(vr.y) + pa.w * bhi(vr.y)
                    + pb.x * blo(vr.z) + pb.y * bhi(vr.z)
                    + pb.z * blo(vr.w) + pb.w * bhi(vr.w);
            }
            if (c == 1) {
                float p256 = psh[wv * 136 + 128];
                pv += p256 * s2f(Vt[lane * 136 + 128]);
            }
            float o_new = o_old * alpha + pv;
            if (c == 0) {
                st_o[(wv * 17 + qi) * 64 + lane] = o_new;
                if (lane == 0) {
                    st_ml[(wv * 17 + qi) * 2 + 0] = m_new;
                    st_ml[(wv * 17 + qi) * 2 + 1] = l_new;
                }
            } else {
                ob[((size_t)(b * S_ + q)) * D_ + hh * HD_ + lane] = o_new / l_new;
            }
        }
        __syncthreads();
    }
}

// ---------------------------------------------------------------- launch
extern "C" void kernel_launch(void* const* d_in, const int* in_sizes, int n_in,
                              void* d_out, int out_size, void* d_ws, size_t ws_size,
                              hipStream_t stream)
{
    const int*   x         = (const int*)d_in[0];
    const float* attn_bias = (const float*)d_in[1];
    const int*   spatial   = (const int*)d_in[2];
    const int*   edget     = (const int*)d_in[3];
    const int*   indeg     = (const int*)d_in[4];
    const int*   outdeg    = (const int*)d_in[5];
    const float* atom_emb  = (const float*)d_in[6];
    const float* ine       = (const float*)d_in[7];
    const float* oute      = (const float*)d_in[8];
    const float* gtok      = (const float*)d_in[9];
    const float* spemb     = (const float*)d_in[10];
    const float* eemb      = (const float*)d_in[11];
    const float* virt      = (const float*)d_in[12];
    const float* Wq        = (const float*)d_in[13];
    const float* Wk        = (const float*)d_in[14];
    const float* Wv        = (const float*)d_in[15];
    const float* Wo        = (const float*)d_in[16];
    const float* bq        = (const float*)d_in[17];
    const float* bk        = (const float*)d_in[18];
    const float* bvv       = (const float*)d_in[19];
    const float* bo        = (const float*)d_in[20];
    const float* ln1g      = (const float*)d_in[21];
    const float* ln1b      = (const float*)d_in[22];
    const float* ln2g      = (const float*)d_in[23];
    const float* ln2b      = (const float*)d_in[24];
    const float* W1        = (const float*)d_in[25];
    const float* b1        = (const float*)d_in[26];
    const float* W2        = (const float*)d_in[27];
    const float* b2        = (const float*)d_in[28];
    const float* fing      = (const float*)d_in[29];
    const float* finb      = (const float*)d_in[30];

    const int M = B_ * S_;          // 8224
    char* wsp = (char*)d_ws;
    size_t off = 0;
    auto alloc = [&](size_t bytes) -> void* {
        void* p = (void*)(wsp + off);
        off += (bytes + 255) & ~(size_t)255;
        return p;
    };
    // ws: h 25.3 + z 25.3 + q/k/v 75.8 + bias bf16 50.7 = ~177 MB (proven safe)
    float* h    = (float*)alloc((size_t)M * D_ * 4);
    float* z    = (float*)alloc((size_t)M * D_ * 4);   // also obuf
    float* qbuf = (float*)alloc((size_t)M * D_ * 4);
    float* kbuf = (float*)alloc((size_t)M * D_ * 4);
    float* vbuf = (float*)alloc((size_t)M * D_ * 4);
    bf16*  bias = (bf16*)alloc((size_t)B_ * H_ * S_ * S_ * 2);
    float* obuf = z;                                   // z dead after V-GEMM
    bf16*  fbuf = (bf16*)qbuf;                         // qkv dead after attn

    embed_kernel<<<M, 256, 0, stream>>>(x, indeg, outdeg, atom_emb, ine, oute, gtok, h);
    bias_kernel<<<M, 256, 0, stream>>>(x, attn_bias, spatial, edget, spemb, eemb, virt, bias);

    dim3 gD((M + 127) / 128, D_ / 128);    // 65 x 6
    dim3 gF((M + 127) / 128, FF_ / 128);   // 65 x 24
    dim3 gA(4, B_ * H_);                   // 4 q-quarters x 384

    for (int l = 0; l < L_; l++) {
        ln_kernel<<<M, 256, 0, stream>>>(h, z, ln1g + l * D_, ln1b + l * D_);
        mgemm<float, float, 1><<<gD, 256, 0, stream>>>(z, Wq + (size_t)l * D_ * D_, bq + l * D_, nullptr, qbuf, M, D_, D_, SCALE_);
        mgemm<float, float, 0><<<gD, 256, 0, stream>>>(z, Wk + (size_t)l * D_ * D_, bk + l * D_, nullptr, kbuf, M, D_, D_, 1.f);
        mgemm<float, float, 0><<<gD, 256, 0, stream>>>(z, Wv + (size_t)l * D_ * D_, bvv + l * D_, nullptr, vbuf, M, D_, D_, 1.f);
        attn2<<<gA, 256, 0, stream>>>(qbuf, kbuf, vbuf, bias, obuf);
        mgemm<float, float, 3><<<gD, 256, 0, stream>>>(obuf, Wo + (size_t)l * D_ * D_, bo + l * D_, h, h, M, D_, D_, 1.f);
        ln_kernel<<<M, 256, 0, stream>>>(h, z, ln2g + l * D_, ln2b + l * D_);
        mgemm<float, bf16, 2><<<gF, 256, 0, stream>>>(z, W1 + (size_t)l * FF_ * D_, b1 + l * FF_, nullptr, fbuf, M, FF_, D_, 1.f);
        mgemm<bf16, float, 3><<<gD, 256, 0, stream>>>(fbuf, W2 + (size_t)l * D_ * FF_, b2 + l * D_, h, h, M, D_, FF_, 1.f);
    }
    final_ln_kernel<<<M, 256, 0, stream>>>(h, fing, finb, (float*)d_out);
}